// Round 1
// baseline (418.944 us; speedup 1.0000x reference)
//
#include <hip/hip_runtime.h>

// RelatEntAtt: E=4096, R=64, D=256. Fully fused recompute; att (E,R,D) never
// materialized. No max-subtraction needed (|att| <~ 20, sums <~ 2e12, fp32-safe);
// exp2 with log2(e) folded into the adj-softmax output (leaky commutes with
// positive scale).
// R2: j tiled in 16s so private arrays SROA-promote to regs.
// R3: grid was the occupancy cap (512 blocks = 2 blocks/CU = 18% occ, VALUBusy 57%).
//     CH 8->4 doubles blocks/CU to 4 (16 waves/CU). IEEE divides (64/thread in kB)
//     -> v_rcp_f32. k_adj folded into kA/kB (wave-per-row adj softmax recompute,
//     identical math in both so normalization is consistent); kR folded into kAlpha.
//     6 -> 4 dispatches.

#define EN 4096
#define RN 64
#define DN 256
#define JT 16          // j-tile width (SROA-friendly)
#define NJT (RN/JT)    // 4 tiles
#define LOG2E 1.44269504088896340736f
#define CH 4           // e's per block in kA/kB -> grid 1024 (4 blocks/CU)

static_assert(CH == 4, "adj-softmax prologue maps one wave per e-row; needs CH==4");

__device__ __forceinline__ float ex2(float x){ return __builtin_amdgcn_exp2f(x); }
__device__ __forceinline__ float rcpf(float x){ return __builtin_amdgcn_rcpf(x); }

template<int CTRL>
__device__ __forceinline__ float dpp_add(float v){
  int m = __builtin_amdgcn_update_dpp(0, __float_as_int(v), CTRL, 0xf, 0xf, true);
  return v + __int_as_float(m);
}
// lane (i%16)==15 ends with the sum of its 16-lane row
__device__ __forceinline__ float row16_sum(float v){
  v = dpp_add<0x111>(v);
  v = dpp_add<0x112>(v);
  v = dpp_add<0x114>(v);
  v = dpp_add<0x118>(v);
  return v;
}

// block-local adj softmax: wave w computes row e0+w -> s2s[w*RN + lane]
// (s2[e,j] = softmax_j(adj[e,:]) * LOG2E; recomputed identically in kA and kB)
__device__ __forceinline__ void adj_sm(const float* __restrict__ adj, int e0,
                                       float* __restrict__ s2s, int tid){
  const int w = tid >> 6, lane = tid & 63;
  float a  = adj[(e0 + w)*RN + lane];
  float ev = ex2(a * LOG2E);
  float s  = ev;
  #pragma unroll
  for(int off = 32; off > 0; off >>= 1) s += __shfl_xor(s, off, 64);
  s2s[w*RN + lane] = ev * (LOG2E * rcpf(s));
}

// ---- kA: invlR[e,d] = 1/sum_j ev;  lE[j,d] += ev (atomics) ----
__global__ __launch_bounds__(256,4) void kA(const float* __restrict__ h,
                                            const float* __restrict__ r,
                                            const float* __restrict__ adj,
                                            float* __restrict__ invlR,
                                            float* __restrict__ lE){
  const int d  = threadIdx.x;
  const int e0 = blockIdx.x * CH;
  __shared__ float s2s[CH*RN];             // 1 KB
  adj_sm(adj, e0, s2s, d);
  __syncthreads();

  float lR[CH];
  #pragma unroll
  for(int ee = 0; ee < CH; ee++) lR[ee] = 0.f;

  #pragma unroll
  for(int jt = 0; jt < NJT; jt++){
    float rcol[JT], lEacc[JT];
    #pragma unroll
    for(int jj = 0; jj < JT; jj++){ rcol[jj] = r[(jt*JT+jj)*DN + d]; lEacc[jj] = 0.f; }
    #pragma unroll
    for(int ee = 0; ee < CH; ee++){
      const float he = h[(e0+ee)*DN + d];
      #pragma unroll
      for(int jg = 0; jg < JT/4; jg++){
        const float4 s4 = *reinterpret_cast<const float4*>(&s2s[ee*RN + jt*JT + jg*4]);
        #pragma unroll
        for(int jj4 = 0; jj4 < 4; jj4++){
          const int jj = jg*4 + jj4;
          const float sv = (jj4==0)?s4.x:(jj4==1)?s4.y:(jj4==2)?s4.z:s4.w;
          float t  = sv * he * rcol[jj];
          float ev = ex2(fmaxf(t, 0.2f*t));
          lR[ee]    += ev;
          lEacc[jj] += ev;
        }
      }
    }
    #pragma unroll
    for(int jj = 0; jj < JT; jj++) atomicAdd(&lE[(jt*JT+jj)*DN + d], lEacc[jj]);
  }
  #pragma unroll
  for(int ee = 0; ee < CH; ee++) invlR[(e0+ee)*DN + d] = rcpf(lR[ee]);
}

// ---- kB: main fused sweep ----
// per (e,d): pR = ev*invlR (att_R), pE = ev/lE (att_E)
//   h'[e,d]  = elu(h * sum_j pE)     coalesced store after tile loop
//   r'[j,d] += pR                    16-reg acc per tile, atomic flush
//   alog[e,j] = sum_d pR*W_d         row16 DPP + LDS partial combine
__global__ __launch_bounds__(256,4) void kB(const float* __restrict__ h,
                                            const float* __restrict__ r,
                                            const float* __restrict__ adj,
                                            const float* __restrict__ invlR,
                                            const float* __restrict__ lE,
                                            const float* __restrict__ W,
                                            float* __restrict__ hout,
                                            float* __restrict__ alog,
                                            float* __restrict__ racc_g){
  const int tid  = threadIdx.x;            // = d
  const int lane = tid & 63;
  const int grp  = tid >> 4;               // 16 groups of 16 lanes
  const int e0   = blockIdx.x * CH;
  __shared__ float s2s[CH*RN];             // 1 KB
  __shared__ float apart[CH*16*20];        // [ee][g][jj], jj stride 1, g stride 20 -> 5 KB
  adj_sm(adj, e0, s2s, tid);
  __syncthreads();

  const float wd = W[tid];
  float sE[CH];
  #pragma unroll
  for(int ee = 0; ee < CH; ee++) sE[ee] = 0.f;

  #pragma unroll
  for(int jt = 0; jt < NJT; jt++){
    float rcol[JT], ile[JT], rAcc[JT];
    #pragma unroll
    for(int jj = 0; jj < JT; jj++){
      const int j = jt*JT + jj;
      rcol[jj] = r[j*DN + tid];
      ile[jj]  = rcpf(lE[j*DN + tid]);
      rAcc[jj] = 0.f;
    }
    for(int ee = 0; ee < CH; ee++){
      const int e = e0 + ee;
      const float he = h[e*DN + tid];
      const float il = invlR[e*DN + tid];
      const float u  = il * wd;
      #pragma unroll
      for(int jg = 0; jg < JT/4; jg++){
        const float4 s4 = *reinterpret_cast<const float4*>(&s2s[ee*RN + jt*JT + jg*4]);
        float4 st;
        #pragma unroll
        for(int jj4 = 0; jj4 < 4; jj4++){
          const int jj = jg*4 + jj4;
          const float sv = (jj4==0)?s4.x:(jj4==1)?s4.y:(jj4==2)?s4.z:s4.w;
          float t  = sv * he * rcol[jj];
          float ev = ex2(fmaxf(t, 0.2f*t));
          rAcc[jj] = fmaf(ev, il, rAcc[jj]);      // pR accumulated over e
          sE[ee]   = fmaf(ev, ile[jj], sE[ee]);   // pE sum over j
          float rs = row16_sum(ev * u);           // alog contribution
          if(jj4==0) st.x = rs; else if(jj4==1) st.y = rs;
          else if(jj4==2) st.z = rs; else st.w = rs;
        }
        if((lane & 15) == 15){
          *reinterpret_cast<float4*>(&apart[(ee*16 + grp)*20 + jg*4]) = st;
        }
      }
    }
    __syncthreads();
    if(tid < CH*JT){                         // 64 threads: ee = tid>>4, jj = tid&15
      const int ee = tid >> 4, jj = tid & 15;
      float sum = 0.f;
      #pragma unroll
      for(int g = 0; g < 16; g++) sum += apart[(ee*16 + g)*20 + jj];
      alog[(e0+ee)*RN + jt*JT + jj] = sum;
    }
    __syncthreads();
    #pragma unroll
    for(int jj = 0; jj < JT; jj++) atomicAdd(&racc_g[(jt*JT+jj)*DN + tid], rAcc[jj]);
  }
  #pragma unroll
  for(int ee = 0; ee < CH; ee++){
    const int e = e0 + ee;
    float hp = h[e*DN + tid] * sE[ee];       // h reload is L1-hot
    hout[e*DN + tid] = hp > 0.f ? hp : (ex2(hp*LOG2E) - 1.0f);
  }
}

// ---- alpha softmax over each contiguous 4096-chunk of flat alog, + fused kR ----
// (reference's reshape(R,E,1)+softmax(axis=1) == this on the e*64+j flat array;
//  b_lin dropped by shift invariance). Block rr also writes rout row rr.
__global__ __launch_bounds__(256) void kAlphaR(const float* __restrict__ alog,
                                               const float* __restrict__ r,
                                               const float* __restrict__ racc,
                                               float* __restrict__ aout,
                                               float* __restrict__ rout){
  const int rr = blockIdx.x, tid = threadIdx.x;
  {
    const int i = rr*DN + tid;
    float v = r[i] * racc[i];
    rout[i] = v > 0.f ? v : (ex2(v*LOG2E) - 1.0f);
  }
  const float* __restrict__ row = alog + rr*EN;
  float exv[16]; float s = 0.f;
  #pragma unroll
  for(int k = 0; k < 16; k++){
    float v = ex2(row[k*256 + tid] * LOG2E);
    exv[k] = v; s += v;
  }
  #pragma unroll
  for(int off = 32; off > 0; off >>= 1) s += __shfl_xor(s, off, 64);
  __shared__ float wsum[4];
  if((tid & 63) == 0) wsum[tid>>6] = s;
  __syncthreads();
  float inv = 1.0f / (wsum[0] + wsum[1] + wsum[2] + wsum[3]);
  float* __restrict__ orow = aout + rr*EN;
  #pragma unroll
  for(int k = 0; k < 16; k++) orow[k*256 + tid] = exv[k] * inv;
}

extern "C" void kernel_launch(void* const* d_in, const int* in_sizes, int n_in,
                              void* d_out, int out_size, void* d_ws, size_t ws_size,
                              hipStream_t stream){
  (void)in_sizes; (void)n_in; (void)out_size; (void)ws_size;
  const float* h   = (const float*)d_in[0];
  const float* r   = (const float*)d_in[1];
  const float* adj = (const float*)d_in[2];
  const float* W   = (const float*)d_in[3];
  // d_in[4] = b_lin: unused (softmax shift invariance)

  float* ws    = (float*)d_ws;
  float* invlR = ws;                 // EN*DN
  float* lE    = invlR + EN*DN;      // RN*DN
  float* racc  = lE + RN*DN;         // RN*DN (adjacent to lE for single memset)
  float* alog  = racc + RN*DN;       // EN*RN

  float* hout = (float*)d_out;           // EN*DN
  float* rout = hout + EN*DN;            // RN*DN
  float* aout = rout + RN*DN;            // RN*EN

  hipMemsetAsync(lE, 0, size_t(RN*DN*2)*sizeof(float), stream); // lE + racc

  kA     <<<EN/CH, 256, 0, stream>>>(h, r, adj, invlR, lE);
  kB     <<<EN/CH, 256, 0, stream>>>(h, r, adj, invlR, lE, W, hout, alog, racc);
  kAlphaR<<<RN,    256, 0, stream>>>(alog, r, racc, aout, rout);
}

// Round 2
// 314.654 us; speedup vs baseline: 1.3314x; 1.3314x over previous
//
#include <hip/hip_runtime.h>

// RelatEntAtt: E=4096, R=64, D=256. Fully fused recompute; att (E,R,D) never
// materialized. No max-subtraction needed (|att| <~ 20, sums <~ 2e12, fp32-safe);
// exp2 with log2(e) folded into the adj-softmax output (leaky commutes with
// positive scale).
// R2: j tiled in 16s so private arrays SROA-promote to regs (64-elem arrays
//     spilled to scratch: 176 MB spill traffic).
// R3 (FAILED, 419us): CH 8->4 + adj-softmax fold + float4 LDS reads together
//     re-broke SROA -> ~520 MB scratch traffic in kA/kB (FETCH 5->221 MB,
//     VALUBusy 57->12%). Lesson: hot-loop codegen here is fragile; change one
//     thing at a time.
// R4: R2 inner loops VERBATIM (separate k_adj, scalar s2s reads). Only changes:
//     CHA/CHB 8->4 (grid 1024 -> 4 blocks/CU; R2 was grid-capped at 18% occ),
//     IEEE divides -> v_rcp_f32 (64/thread in kB, ~600 VALU instrs; numerics
//     validated in R3), kR folded into kAlpha (cold kernel only).

#define EN 4096
#define RN 64
#define DN 256
#define JT 16          // j-tile width (SROA-friendly)
#define NJT (RN/JT)    // 4 tiles
#define LOG2E 1.44269504088896340736f
#define CHA 4   // e's per block in kA  -> grid 1024
#define CHB 4   // e's per block in kB  -> grid 1024

__device__ __forceinline__ float ex2(float x){ return __builtin_amdgcn_exp2f(x); }
__device__ __forceinline__ float rcpf(float x){ return __builtin_amdgcn_rcpf(x); }

template<int CTRL>
__device__ __forceinline__ float dpp_add(float v){
  int m = __builtin_amdgcn_update_dpp(0, __float_as_int(v), CTRL, 0xf, 0xf, true);
  return v + __int_as_float(m);
}
// lane (i%16)==15 ends with the sum of its 16-lane row
__device__ __forceinline__ float row16_sum(float v){
  v = dpp_add<0x111>(v);
  v = dpp_add<0x112>(v);
  v = dpp_add<0x114>(v);
  v = dpp_add<0x118>(v);
  return v;
}

// ---- s2[e,j] = softmax_j(adj[e,:]) * LOG2E ----
__global__ __launch_bounds__(256) void k_adj(const float* __restrict__ adj,
                                             float* __restrict__ s2){
  const int lane = threadIdx.x & 63;
  const int e = blockIdx.x*4 + (threadIdx.x >> 6);
  float a = adj[e*RN + lane];
  float ev = ex2(a * LOG2E);
  float s = ev;
  #pragma unroll
  for(int off = 32; off > 0; off >>= 1) s += __shfl_xor(s, off, 64);
  s2[e*RN + lane] = ev * (LOG2E * rcpf(s));
}

// ---- kA: invlR[e,d] = 1/sum_j ev;  lE[j,d] += ev (atomics) ----
__global__ __launch_bounds__(256,4) void kA(const float* __restrict__ h,
                                            const float* __restrict__ r,
                                            const float* __restrict__ s2,
                                            float* __restrict__ invlR,
                                            float* __restrict__ lE){
  const int d = threadIdx.x;
  const int e0 = blockIdx.x * CHA;
  __shared__ float s2s[CHA*RN];            // 1 KB
  #pragma unroll
  for(int k = 0; k < CHA*RN/256; k++) s2s[k*256 + d] = s2[e0*RN + k*256 + d];
  __syncthreads();

  float lR[CHA];
  #pragma unroll
  for(int ee = 0; ee < CHA; ee++) lR[ee] = 0.f;

  #pragma unroll
  for(int jt = 0; jt < NJT; jt++){
    float rcol[JT], lEacc[JT];
    #pragma unroll
    for(int jj = 0; jj < JT; jj++){ rcol[jj] = r[(jt*JT+jj)*DN + d]; lEacc[jj] = 0.f; }
    #pragma unroll
    for(int ee = 0; ee < CHA; ee++){
      const float he = h[(e0+ee)*DN + d];
      #pragma unroll
      for(int jj = 0; jj < JT; jj++){
        float t  = s2s[ee*RN + jt*JT + jj] * he * rcol[jj];
        float ev = ex2(fmaxf(t, 0.2f*t));
        lR[ee]   += ev;
        lEacc[jj] += ev;
      }
    }
    #pragma unroll
    for(int jj = 0; jj < JT; jj++) atomicAdd(&lE[(jt*JT+jj)*DN + d], lEacc[jj]);
  }
  #pragma unroll
  for(int ee = 0; ee < CHA; ee++) invlR[(e0+ee)*DN + d] = rcpf(lR[ee]);
}

// ---- kB: main fused sweep ----
// per (e,d): pR = ev*invlR (att_R), pE = ev/lE (att_E)
//   h'[e,d]  = elu(h * sum_j pE)     coalesced store after tile loop
//   r'[j,d] += pR                    16-reg acc per tile, atomic flush
//   alog[e,j] = sum_d pR*W_d         row16 DPP + LDS partial combine
__global__ __launch_bounds__(256,4) void kB(const float* __restrict__ h,
                                            const float* __restrict__ r,
                                            const float* __restrict__ s2,
                                            const float* __restrict__ invlR,
                                            const float* __restrict__ lE,
                                            const float* __restrict__ W,
                                            float* __restrict__ hout,
                                            float* __restrict__ alog,
                                            float* __restrict__ racc_g){
  const int tid  = threadIdx.x;            // = d
  const int lane = tid & 63;
  const int grp  = tid >> 4;               // 16 groups of 16 lanes
  const int e0   = blockIdx.x * CHB;
  __shared__ float s2s[CHB*RN];            // 1 KB
  __shared__ float apart[CHB*16*20];       // [ee][g][jj], jj stride 1, g stride 20 -> 5 KB
  #pragma unroll
  for(int k = 0; k < CHB*RN/256; k++) s2s[k*256 + tid] = s2[e0*RN + k*256 + tid];
  __syncthreads();

  const float wd = W[tid];
  float sE[CHB];
  #pragma unroll
  for(int ee = 0; ee < CHB; ee++) sE[ee] = 0.f;

  #pragma unroll
  for(int jt = 0; jt < NJT; jt++){
    float rcol[JT], ile[JT], rAcc[JT];
    #pragma unroll
    for(int jj = 0; jj < JT; jj++){
      const int j = jt*JT + jj;
      rcol[jj] = r[j*DN + tid];
      ile[jj]  = rcpf(lE[j*DN + tid]);
      rAcc[jj] = 0.f;
    }
    for(int ee = 0; ee < CHB; ee++){
      const int e = e0 + ee;
      const float he = h[e*DN + tid];
      const float il = invlR[e*DN + tid];
      const float u  = il * wd;
      #pragma unroll
      for(int jg = 0; jg < JT/4; jg++){
        float4 st;
        #pragma unroll
        for(int jj4 = 0; jj4 < 4; jj4++){
          const int jj = jg*4 + jj4;
          float t  = s2s[ee*RN + jt*JT + jj] * he * rcol[jj];
          float ev = ex2(fmaxf(t, 0.2f*t));
          rAcc[jj] = fmaf(ev, il, rAcc[jj]);      // pR accumulated over e
          sE[ee]   = fmaf(ev, ile[jj], sE[ee]);   // pE sum over j
          float rs = row16_sum(ev * u);           // alog contribution
          if(jj4==0) st.x = rs; else if(jj4==1) st.y = rs;
          else if(jj4==2) st.z = rs; else st.w = rs;
        }
        if((lane & 15) == 15){
          *reinterpret_cast<float4*>(&apart[(ee*16 + grp)*20 + jg*4]) = st;
        }
      }
    }
    __syncthreads();
    if(tid < CHB*JT){                        // 64 threads: ee = tid>>4, jj = tid&15
      const int ee = tid >> 4, jj = tid & 15;
      float sum = 0.f;
      #pragma unroll
      for(int g = 0; g < 16; g++) sum += apart[(ee*16 + g)*20 + jj];
      alog[(e0+ee)*RN + jt*JT + jj] = sum;
    }
    __syncthreads();
    #pragma unroll
    for(int jj = 0; jj < JT; jj++) atomicAdd(&racc_g[(jt*JT+jj)*DN + tid], rAcc[jj]);
  }
  #pragma unroll
  for(int ee = 0; ee < CHB; ee++){
    const int e = e0 + ee;
    float hp = h[e*DN + tid] * sE[ee];       // h reload is L1-hot
    hout[e*DN + tid] = hp > 0.f ? hp : (ex2(hp*LOG2E) - 1.0f);
  }
}

// ---- alpha softmax over each contiguous 4096-chunk of flat alog, + fused kR ----
// (reference's reshape(R,E,1)+softmax(axis=1) == this on the e*64+j flat array;
//  b_lin dropped by shift invariance). Block rr also writes rout row rr.
__global__ __launch_bounds__(256) void kAlphaR(const float* __restrict__ alog,
                                               const float* __restrict__ r,
                                               const float* __restrict__ racc,
                                               float* __restrict__ aout,
                                               float* __restrict__ rout){
  const int rr = blockIdx.x, tid = threadIdx.x;
  {
    const int i = rr*DN + tid;
    float v = r[i] * racc[i];
    rout[i] = v > 0.f ? v : (ex2(v*LOG2E) - 1.0f);
  }
  const float* __restrict__ row = alog + rr*EN;
  float exv[16]; float s = 0.f;
  #pragma unroll
  for(int k = 0; k < 16; k++){
    float v = ex2(row[k*256 + tid] * LOG2E);
    exv[k] = v; s += v;
  }
  #pragma unroll
  for(int off = 32; off > 0; off >>= 1) s += __shfl_xor(s, off, 64);
  __shared__ float wsum[4];
  if((tid & 63) == 0) wsum[tid>>6] = s;
  __syncthreads();
  float inv = 1.0f / (wsum[0] + wsum[1] + wsum[2] + wsum[3]);
  float* __restrict__ orow = aout + rr*EN;
  #pragma unroll
  for(int k = 0; k < 16; k++) orow[k*256 + tid] = exv[k] * inv;
}

extern "C" void kernel_launch(void* const* d_in, const int* in_sizes, int n_in,
                              void* d_out, int out_size, void* d_ws, size_t ws_size,
                              hipStream_t stream){
  (void)in_sizes; (void)n_in; (void)out_size; (void)ws_size;
  const float* h   = (const float*)d_in[0];
  const float* r   = (const float*)d_in[1];
  const float* adj = (const float*)d_in[2];
  const float* W   = (const float*)d_in[3];
  // d_in[4] = b_lin: unused (softmax shift invariance)

  float* ws    = (float*)d_ws;
  float* s2    = ws;                 // EN*RN
  float* invlR = s2 + EN*RN;         // EN*DN
  float* lE    = invlR + EN*DN;      // RN*DN
  float* racc  = lE + RN*DN;         // RN*DN (adjacent for single memset)
  float* alog  = racc + RN*DN;       // EN*RN

  float* hout = (float*)d_out;           // EN*DN
  float* rout = hout + EN*DN;            // RN*DN
  float* aout = rout + RN*DN;            // RN*EN

  hipMemsetAsync(lE, 0, size_t(RN*DN*2)*sizeof(float), stream); // lE + racc

  k_adj  <<<EN/4,   256, 0, stream>>>(adj, s2);
  kA     <<<EN/CHA, 256, 0, stream>>>(h, r, s2, invlR, lE);
  kB     <<<EN/CHB, 256, 0, stream>>>(h, r, s2, invlR, lE, W, hout, alog, racc);
  kAlphaR<<<RN,     256, 0, stream>>>(alog, r, racc, aout, rout);
}

// Round 3
// 181.408 us; speedup vs baseline: 2.3094x; 1.7345x over previous
//
#include <hip/hip_runtime.h>

// RelatEntAtt: E=4096, R=64, D=256. Fully fused recompute; att (E,R,D) never
// materialized. exp2 with log2(e) folded into the adj-softmax output.
// R2 (180.9us, proven): CH=8, j tiled in 16s, arrays SROA to regs. Grid 512
//     -> 18% occ, VALUBusy 57% -> latency-bound.
// R3/R4 (FAILED 419/315us): CH=4 breaks SROA regardless of other edits
//     (~470 MB scratch traffic, VALUBusy ~11%). CH=8 body is load-bearing;
//     DO NOT change CHA/CHB or the inner-loop shapes.
// R5: occupancy via j-split instead: each kA/kB block handles 32 of 64 j's
//     (2 of 4 jt tiles), grid 1024 -> 4 blocks/CU, 16 waves/CU. Inner bodies
//     verbatim R2. Cross-block j-sums (lR, sE) -> global atomics (lRg, sEg);
//     alog/racc/lE owned per-j, unchanged. Tail kernel: hout ELU + rout + alpha.

#define EN 4096
#define RN 64
#define DN 256
#define JT 16          // j-tile width (SROA-friendly)
#define LOG2E 1.44269504088896340736f
#define CHA 8   // e's per block in kA (PROVEN SROA shape - do not change)
#define CHB 8   // e's per block in kB (PROVEN SROA shape - do not change)

__device__ __forceinline__ float ex2(float x){ return __builtin_amdgcn_exp2f(x); }
__device__ __forceinline__ float rcpf(float x){ return __builtin_amdgcn_rcpf(x); }

template<int CTRL>
__device__ __forceinline__ float dpp_add(float v){
  int m = __builtin_amdgcn_update_dpp(0, __float_as_int(v), CTRL, 0xf, 0xf, true);
  return v + __int_as_float(m);
}
// lane (i%16)==15 ends with the sum of its 16-lane row
__device__ __forceinline__ float row16_sum(float v){
  v = dpp_add<0x111>(v);
  v = dpp_add<0x112>(v);
  v = dpp_add<0x114>(v);
  v = dpp_add<0x118>(v);
  return v;
}

// ---- s2[e,j] = softmax_j(adj[e,:]) * LOG2E ----
__global__ __launch_bounds__(256) void k_adj(const float* __restrict__ adj,
                                             float* __restrict__ s2){
  const int lane = threadIdx.x & 63;
  const int e = blockIdx.x*4 + (threadIdx.x >> 6);
  float a = adj[e*RN + lane];
  float ev = ex2(a * LOG2E);
  float s = ev;
  #pragma unroll
  for(int off = 32; off > 0; off >>= 1) s += __shfl_xor(s, off, 64);
  s2[e*RN + lane] = ev * (LOG2E * rcpf(s));
}

// ---- kA: lRg[e,d] += sum_(own j) ev;  lE[j,d] += ev ----
// block = (e-chunk, j-half): e0 = (bid>>1)*CHA, j range = (bid&1)*32 .. +32
__global__ __launch_bounds__(256,4) void kA(const float* __restrict__ h,
                                            const float* __restrict__ r,
                                            const float* __restrict__ s2,
                                            float* __restrict__ lRg,
                                            float* __restrict__ lE){
  const int d  = threadIdx.x;
  const int e0 = (blockIdx.x >> 1) * CHA;
  const int jh = (blockIdx.x & 1) * 32;
  __shared__ float s2s[CHA*32];            // 1 KB
  s2s[d] = s2[(e0 + (d >> 5))*RN + jh + (d & 31)];
  __syncthreads();

  float lR[CHA];
  #pragma unroll
  for(int ee = 0; ee < CHA; ee++) lR[ee] = 0.f;

  #pragma unroll
  for(int jt2 = 0; jt2 < 2; jt2++){
    float rcol[JT], lEacc[JT];
    #pragma unroll
    for(int jj = 0; jj < JT; jj++){ rcol[jj] = r[(jh + jt2*JT + jj)*DN + d]; lEacc[jj] = 0.f; }
    #pragma unroll
    for(int ee = 0; ee < CHA; ee++){
      const float he = h[(e0+ee)*DN + d];
      #pragma unroll
      for(int jj = 0; jj < JT; jj++){
        float t  = s2s[ee*32 + jt2*JT + jj] * he * rcol[jj];
        float ev = ex2(fmaxf(t, 0.2f*t));
        lR[ee]   += ev;
        lEacc[jj] += ev;
      }
    }
    #pragma unroll
    for(int jj = 0; jj < JT; jj++) atomicAdd(&lE[(jh + jt2*JT + jj)*DN + d], lEacc[jj]);
  }
  #pragma unroll
  for(int ee = 0; ee < CHA; ee++) atomicAdd(&lRg[(e0+ee)*DN + d], lR[ee]);
}

// ---- kB: main fused sweep over own j-half ----
// per (e,d): pR = ev/lRg (att_R), pE = ev/lE (att_E)
//   sEg[e,d] += sum_(own j) pE      (atomics; h' ELU in kTail)
//   r'[j,d] += pR                   16-reg acc per tile, atomic flush
//   alog[e,j] = sum_d pR*W_d        row16 DPP + LDS partial combine (j owned)
__global__ __launch_bounds__(256,4) void kB(const float* __restrict__ h,
                                            const float* __restrict__ r,
                                            const float* __restrict__ s2,
                                            const float* __restrict__ lRg,
                                            const float* __restrict__ lE,
                                            const float* __restrict__ W,
                                            float* __restrict__ alog,
                                            float* __restrict__ racc_g,
                                            float* __restrict__ sEg){
  const int tid  = threadIdx.x;            // = d
  const int lane = tid & 63;
  const int grp  = tid >> 4;               // 16 groups of 16 lanes
  const int e0   = (blockIdx.x >> 1) * CHB;
  const int jh   = (blockIdx.x & 1) * 32;
  __shared__ float s2s[CHB*32];            // 1 KB
  __shared__ float apart[CHB*16*20];       // [ee][g][jj], jj stride 1, g stride 20 -> 10 KB
  s2s[tid] = s2[(e0 + (tid >> 5))*RN + jh + (tid & 31)];
  __syncthreads();

  const float wd = W[tid];
  float sE[CHB];
  #pragma unroll
  for(int ee = 0; ee < CHB; ee++) sE[ee] = 0.f;

  #pragma unroll
  for(int jt2 = 0; jt2 < 2; jt2++){
    float rcol[JT], ile[JT], rAcc[JT];
    #pragma unroll
    for(int jj = 0; jj < JT; jj++){
      const int j = jh + jt2*JT + jj;
      rcol[jj] = r[j*DN + tid];
      ile[jj]  = rcpf(lE[j*DN + tid]);
      rAcc[jj] = 0.f;
    }
    for(int ee = 0; ee < CHB; ee++){
      const int e = e0 + ee;
      const float he = h[e*DN + tid];
      const float il = rcpf(lRg[e*DN + tid]);
      const float u  = il * wd;
      #pragma unroll
      for(int jg = 0; jg < JT/4; jg++){
        float4 st;
        #pragma unroll
        for(int jj4 = 0; jj4 < 4; jj4++){
          const int jj = jg*4 + jj4;
          float t  = s2s[ee*32 + jt2*JT + jj] * he * rcol[jj];
          float ev = ex2(fmaxf(t, 0.2f*t));
          rAcc[jj] = fmaf(ev, il, rAcc[jj]);      // pR accumulated over e
          sE[ee]   = fmaf(ev, ile[jj], sE[ee]);   // pE sum over own j
          float rs = row16_sum(ev * u);           // alog contribution
          if(jj4==0) st.x = rs; else if(jj4==1) st.y = rs;
          else if(jj4==2) st.z = rs; else st.w = rs;
        }
        if((lane & 15) == 15){
          *reinterpret_cast<float4*>(&apart[(ee*16 + grp)*20 + jg*4]) = st;
        }
      }
    }
    __syncthreads();
    if(tid < CHB*JT){                        // 128 threads: ee = tid>>4, jj = tid&15
      const int ee = tid >> 4, jj = tid & 15;
      float sum = 0.f;
      #pragma unroll
      for(int g = 0; g < 16; g++) sum += apart[(ee*16 + g)*20 + jj];
      alog[(e0+ee)*RN + jh + jt2*JT + jj] = sum;
    }
    __syncthreads();
    #pragma unroll
    for(int jj = 0; jj < JT; jj++) atomicAdd(&racc_g[(jh + jt2*JT + jj)*DN + tid], rAcc[jj]);
  }
  #pragma unroll
  for(int ee = 0; ee < CHB; ee++) atomicAdd(&sEg[(e0+ee)*DN + tid], sE[ee]);
}

// ---- tail: hout = elu(h*sEg) everywhere; blocks 0..63 also do rout + alpha ----
// (reference's reshape(R,E,1)+softmax(axis=1) == per-row softmax on the e*64+j
//  flat array viewed as [64][4096]; b_lin dropped by shift invariance)
__global__ __launch_bounds__(256) void kTail(const float* __restrict__ h,
                                             const float* __restrict__ sEg,
                                             const float* __restrict__ alog,
                                             const float* __restrict__ r,
                                             const float* __restrict__ racc,
                                             float* __restrict__ hout,
                                             float* __restrict__ rout,
                                             float* __restrict__ aout){
  const int b = blockIdx.x, tid = threadIdx.x;
  {
    const int i = b*256 + tid;               // grid 4096 covers EN*DN
    float hp = h[i] * sEg[i];
    hout[i] = hp > 0.f ? hp : (ex2(hp*LOG2E) - 1.0f);
  }
  if(b < RN){                                 // block-uniform branch
    const int i = b*DN + tid;
    float v = r[i] * racc[i];
    rout[i] = v > 0.f ? v : (ex2(v*LOG2E) - 1.0f);

    const float* __restrict__ row = alog + b*EN;
    float exv[16]; float s = 0.f;
    #pragma unroll
    for(int k = 0; k < 16; k++){
      float v2 = ex2(row[k*256 + tid] * LOG2E);
      exv[k] = v2; s += v2;
    }
    #pragma unroll
    for(int off = 32; off > 0; off >>= 1) s += __shfl_xor(s, off, 64);
    __shared__ float wsum[4];
    if((tid & 63) == 0) wsum[tid>>6] = s;
    __syncthreads();
    float inv = 1.0f / (wsum[0] + wsum[1] + wsum[2] + wsum[3]);
    float* __restrict__ orow = aout + b*EN;
    #pragma unroll
    for(int k = 0; k < 16; k++) orow[k*256 + tid] = exv[k] * inv;
  }
}

extern "C" void kernel_launch(void* const* d_in, const int* in_sizes, int n_in,
                              void* d_out, int out_size, void* d_ws, size_t ws_size,
                              hipStream_t stream){
  (void)in_sizes; (void)n_in; (void)out_size; (void)ws_size;
  const float* h   = (const float*)d_in[0];
  const float* r   = (const float*)d_in[1];
  const float* adj = (const float*)d_in[2];
  const float* W   = (const float*)d_in[3];
  // d_in[4] = b_lin: unused (softmax shift invariance)

  float* ws   = (float*)d_ws;
  float* s2   = ws;                  // EN*RN
  float* lE   = s2 + EN*RN;          // RN*DN  --+
  float* racc = lE + RN*DN;          // RN*DN    | one contiguous memset
  float* lRg  = racc + RN*DN;        // EN*DN    |
  float* sEg  = lRg + EN*DN;         // EN*DN  --+
  float* alog = sEg + EN*DN;         // EN*RN

  float* hout = (float*)d_out;           // EN*DN
  float* rout = hout + EN*DN;            // RN*DN
  float* aout = rout + RN*DN;            // RN*EN

  hipMemsetAsync(lE, 0, size_t(RN*DN*2 + EN*DN*2)*sizeof(float), stream);

  k_adj<<<EN/4,       256, 0, stream>>>(adj, s2);
  kA   <<<EN/CHA*2,   256, 0, stream>>>(h, r, s2, lRg, lE);
  kB   <<<EN/CHB*2,   256, 0, stream>>>(h, r, s2, lRg, lE, W, alog, racc, sEg);
  kTail<<<EN*DN/256,  256, 0, stream>>>(h, sEg, alog, r, racc, hout, rout, aout);
}

// Round 4
// 170.095 us; speedup vs baseline: 2.4630x; 1.0665x over previous
//
#include <hip/hip_runtime.h>

// RelatEntAtt: E=4096, R=64, D=256. Fully fused recompute; att (E,R,D) never
// materialized. exp2 with log2(e) folded into the adj-softmax output.
// R2 (180.9us): CH=8, j tiled in 16s, arrays SROA to regs. Grid 512 -> 18% occ.
// R3/R4 (FAILED): CH=4 breaks SROA regardless of other edits (~470 MB scratch
//     traffic). CH=8 + JT=16 private-array shapes are load-bearing. DO NOT TOUCH.
// R5 (181us): j-half split, grid 1024. kB 73->65us, occ 30%, VALUBusy 61%.
//     SROA held -> orchestration-only changes are safe. ~50us of wall is
//     dispatch gaps (5 launches).
// R6: j-quarter split (one JT=16 tile per block), grid 2048 -> 8 blocks/CU
//     (VGPR=56 allows 8 waves/SIMD). Private array shapes identical to R5.
//     Memset folded into k_adj (grid-stride float4 zero) -> 4 dispatches.

#define EN 4096
#define RN 64
#define DN 256
#define JT 16          // j-tile width (PROVEN SROA shape - do not change)
#define LOG2E 1.44269504088896340736f
#define CHA 8   // e's per block in kA (PROVEN SROA shape - do not change)
#define CHB 8   // e's per block in kB (PROVEN SROA shape - do not change)
#define ZERO_F4 ((RN*DN*2 + EN*DN*2)/4)   // float4 count of zeroed ws region

__device__ __forceinline__ float ex2(float x){ return __builtin_amdgcn_exp2f(x); }
__device__ __forceinline__ float rcpf(float x){ return __builtin_amdgcn_rcpf(x); }

template<int CTRL>
__device__ __forceinline__ float dpp_add(float v){
  int m = __builtin_amdgcn_update_dpp(0, __float_as_int(v), CTRL, 0xf, 0xf, true);
  return v + __int_as_float(m);
}
// lane (i%16)==15 ends with the sum of its 16-lane row
__device__ __forceinline__ float row16_sum(float v){
  v = dpp_add<0x111>(v);
  v = dpp_add<0x112>(v);
  v = dpp_add<0x114>(v);
  v = dpp_add<0x118>(v);
  return v;
}

// ---- s2[e,j] = softmax_j(adj[e,:]) * LOG2E;  also zeroes accumulator ws ----
__global__ __launch_bounds__(256) void k_adj(const float* __restrict__ adj,
                                             float* __restrict__ s2,
                                             float4* __restrict__ zbase){
  const int tid = threadIdx.x;
  const int gt  = blockIdx.x*256 + tid;          // grid 1024 -> 262144 threads
  for(int i = gt; i < ZERO_F4; i += (EN/4)*256)
    zbase[i] = make_float4(0.f, 0.f, 0.f, 0.f);
  const int lane = tid & 63;
  const int e = blockIdx.x*4 + (tid >> 6);
  float a = adj[e*RN + lane];
  float ev = ex2(a * LOG2E);
  float s = ev;
  #pragma unroll
  for(int off = 32; off > 0; off >>= 1) s += __shfl_xor(s, off, 64);
  s2[e*RN + lane] = ev * (LOG2E * rcpf(s));
}

// ---- kA: lRg[e,d] += sum_(own j) ev;  lE[j,d] += ev ----
// block = (e-chunk, j-quarter): e0 = (bid>>2)*CHA, j0 = (bid&3)*16
__global__ __launch_bounds__(256,4) void kA(const float* __restrict__ h,
                                            const float* __restrict__ r,
                                            const float* __restrict__ s2,
                                            float* __restrict__ lRg,
                                            float* __restrict__ lE){
  const int d  = threadIdx.x;
  const int e0 = (blockIdx.x >> 2) * CHA;
  const int j0 = (blockIdx.x & 3) * JT;
  __shared__ float s2s[CHA*JT];            // 512 B
  if(d < CHA*JT) s2s[d] = s2[(e0 + (d >> 4))*RN + j0 + (d & 15)];
  __syncthreads();

  float lR[CHA];
  #pragma unroll
  for(int ee = 0; ee < CHA; ee++) lR[ee] = 0.f;

  float rcol[JT], lEacc[JT];
  #pragma unroll
  for(int jj = 0; jj < JT; jj++){ rcol[jj] = r[(j0+jj)*DN + d]; lEacc[jj] = 0.f; }
  #pragma unroll
  for(int ee = 0; ee < CHA; ee++){
    const float he = h[(e0+ee)*DN + d];
    #pragma unroll
    for(int jj = 0; jj < JT; jj++){
      float t  = s2s[ee*JT + jj] * he * rcol[jj];
      float ev = ex2(fmaxf(t, 0.2f*t));
      lR[ee]   += ev;
      lEacc[jj] += ev;
    }
  }
  #pragma unroll
  for(int jj = 0; jj < JT; jj++) atomicAdd(&lE[(j0+jj)*DN + d], lEacc[jj]);
  #pragma unroll
  for(int ee = 0; ee < CHA; ee++) atomicAdd(&lRg[(e0+ee)*DN + d], lR[ee]);
}

// ---- kB: main fused sweep over own j-quarter ----
// per (e,d): pR = ev/lRg (att_R), pE = ev/lE (att_E)
//   sEg[e,d] += sum_(own j) pE      (atomics; h' ELU in kTail)
//   r'[j,d] += pR                   16-reg acc, atomic flush
//   alog[e,j] = sum_d pR*W_d        row16 DPP + LDS partial combine (j owned)
__global__ __launch_bounds__(256,4) void kB(const float* __restrict__ h,
                                            const float* __restrict__ r,
                                            const float* __restrict__ s2,
                                            const float* __restrict__ lRg,
                                            const float* __restrict__ lE,
                                            const float* __restrict__ W,
                                            float* __restrict__ alog,
                                            float* __restrict__ racc_g,
                                            float* __restrict__ sEg){
  const int tid  = threadIdx.x;            // = d
  const int lane = tid & 63;
  const int grp  = tid >> 4;               // 16 groups of 16 lanes
  const int e0   = (blockIdx.x >> 2) * CHB;
  const int j0   = (blockIdx.x & 3) * JT;
  __shared__ float s2s[CHB*JT];            // 512 B
  __shared__ float apart[CHB*16*20];       // [ee][g][jj], jj stride 1, g stride 20 -> 10 KB
  if(tid < CHB*JT) s2s[tid] = s2[(e0 + (tid >> 4))*RN + j0 + (tid & 15)];
  __syncthreads();

  const float wd = W[tid];
  float sE[CHB];
  #pragma unroll
  for(int ee = 0; ee < CHB; ee++) sE[ee] = 0.f;

  float rcol[JT], ile[JT], rAcc[JT];
  #pragma unroll
  for(int jj = 0; jj < JT; jj++){
    const int j = j0 + jj;
    rcol[jj] = r[j*DN + tid];
    ile[jj]  = rcpf(lE[j*DN + tid]);
    rAcc[jj] = 0.f;
  }
  for(int ee = 0; ee < CHB; ee++){
    const int e = e0 + ee;
    const float he = h[e*DN + tid];
    const float il = rcpf(lRg[e*DN + tid]);
    const float u  = il * wd;
    #pragma unroll
    for(int jg = 0; jg < JT/4; jg++){
      float4 st;
      #pragma unroll
      for(int jj4 = 0; jj4 < 4; jj4++){
        const int jj = jg*4 + jj4;
        float t  = s2s[ee*JT + jj] * he * rcol[jj];
        float ev = ex2(fmaxf(t, 0.2f*t));
        rAcc[jj] = fmaf(ev, il, rAcc[jj]);      // pR accumulated over e
        sE[ee]   = fmaf(ev, ile[jj], sE[ee]);   // pE sum over own j
        float rs = row16_sum(ev * u);           // alog contribution
        if(jj4==0) st.x = rs; else if(jj4==1) st.y = rs;
        else if(jj4==2) st.z = rs; else st.w = rs;
      }
      if((lane & 15) == 15){
        *reinterpret_cast<float4*>(&apart[(ee*16 + grp)*20 + jg*4]) = st;
      }
    }
  }
  __syncthreads();
  if(tid < CHB*JT){                        // 128 threads: ee = tid>>4, jj = tid&15
    const int ee = tid >> 4, jj = tid & 15;
    float sum = 0.f;
    #pragma unroll
    for(int g = 0; g < 16; g++) sum += apart[(ee*16 + g)*20 + jj];
    alog[(e0+ee)*RN + j0 + jj] = sum;
  }
  #pragma unroll
  for(int jj = 0; jj < JT; jj++) atomicAdd(&racc_g[(j0+jj)*DN + tid], rAcc[jj]);
  #pragma unroll
  for(int ee = 0; ee < CHB; ee++) atomicAdd(&sEg[(e0+ee)*DN + tid], sE[ee]);
}

// ---- tail: hout = elu(h*sEg) everywhere; blocks 0..63 also do rout + alpha ----
// (reference's reshape(R,E,1)+softmax(axis=1) == per-row softmax on the e*64+j
//  flat array viewed as [64][4096]; b_lin dropped by shift invariance)
__global__ __launch_bounds__(256) void kTail(const float* __restrict__ h,
                                             const float* __restrict__ sEg,
                                             const float* __restrict__ alog,
                                             const float* __restrict__ r,
                                             const float* __restrict__ racc,
                                             float* __restrict__ hout,
                                             float* __restrict__ rout,
                                             float* __restrict__ aout){
  const int b = blockIdx.x, tid = threadIdx.x;
  {
    const int i = b*256 + tid;               // grid 4096 covers EN*DN
    float hp = h[i] * sEg[i];
    hout[i] = hp > 0.f ? hp : (ex2(hp*LOG2E) - 1.0f);
  }
  if(b < RN){                                 // block-uniform branch
    const int i = b*DN + tid;
    float v = r[i] * racc[i];
    rout[i] = v > 0.f ? v : (ex2(v*LOG2E) - 1.0f);

    const float* __restrict__ row = alog + b*EN;
    float exv[16]; float s = 0.f;
    #pragma unroll
    for(int k = 0; k < 16; k++){
      float v2 = ex2(row[k*256 + tid] * LOG2E);
      exv[k] = v2; s += v2;
    }
    #pragma unroll
    for(int off = 32; off > 0; off >>= 1) s += __shfl_xor(s, off, 64);
    __shared__ float wsum[4];
    if((tid & 63) == 0) wsum[tid>>6] = s;
    __syncthreads();
    float inv = 1.0f / (wsum[0] + wsum[1] + wsum[2] + wsum[3]);
    float* __restrict__ orow = aout + b*EN;
    #pragma unroll
    for(int k = 0; k < 16; k++) orow[k*256 + tid] = exv[k] * inv;
  }
}

extern "C" void kernel_launch(void* const* d_in, const int* in_sizes, int n_in,
                              void* d_out, int out_size, void* d_ws, size_t ws_size,
                              hipStream_t stream){
  (void)in_sizes; (void)n_in; (void)out_size; (void)ws_size;
  const float* h   = (const float*)d_in[0];
  const float* r   = (const float*)d_in[1];
  const float* adj = (const float*)d_in[2];
  const float* W   = (const float*)d_in[3];
  // d_in[4] = b_lin: unused (softmax shift invariance)

  float* ws   = (float*)d_ws;
  float* s2   = ws;                  // EN*RN
  float* lE   = s2 + EN*RN;          // RN*DN  --+
  float* racc = lE + RN*DN;          // RN*DN    | zeroed by k_adj
  float* lRg  = racc + RN*DN;        // EN*DN    |
  float* sEg  = lRg + EN*DN;         // EN*DN  --+
  float* alog = sEg + EN*DN;         // EN*RN

  float* hout = (float*)d_out;           // EN*DN
  float* rout = hout + EN*DN;            // RN*DN
  float* aout = rout + RN*DN;            // RN*EN

  k_adj<<<EN/4,      256, 0, stream>>>(adj, s2, (float4*)lE);
  kA   <<<EN/CHA*4,  256, 0, stream>>>(h, r, s2, lRg, lE);
  kB   <<<EN/CHB*4,  256, 0, stream>>>(h, r, s2, lRg, lE, W, alog, racc, sEg);
  kTail<<<EN*DN/256, 256, 0, stream>>>(h, sEg, alog, r, racc, hout, rout, aout);
}